// Round 6
// baseline (52.877 us; speedup 1.0000x reference)
//
#include <hip/hip_runtime.h>

#define HDIM 1024
#define SDIM 4096
#define BDIM 16
#define NROW (BDIM * SDIM)     // 65536 rows
#define EBLOCKS 2048           // 8 blocks/CU, 8192 waves
#define RPW 8                  // rows per wave: 65536 / (2048*4)

// u[h] = sum_k v[k] * W[k*2H + H + h]
// h-split, atomic-free: block b owns h in [16b, 16b+16). Thread t = (kc, hl),
// kc = t>>4 (16 k-chunks of 64), hl = t&15. LDS-reduce over kc, single store.
__global__ __launch_bounds__(256) void compute_u_kernel(
    const float* __restrict__ W, const float* __restrict__ v,
    float* __restrict__ u) {
    __shared__ float part[16][17];  // [kc][hl], +1 pad
    int t  = threadIdx.x;
    int hl = t & 15;
    int kc = t >> 4;
    int h  = blockIdx.x * 16 + hl;
    float acc = 0.f;
    #pragma unroll 8
    for (int i = 0; i < 64; ++i) {
        int k = kc * 64 + i;
        acc = fmaf(v[k], W[(size_t)k * (2 * HDIM) + HDIM + h], acc);
    }
    part[kc][hl] = acc;
    __syncthreads();
    if (t < 16) {
        float s = 0.f;
        #pragma unroll
        for (int i = 0; i < 16; ++i) s += part[i][t];
        u[blockIdx.x * 16 + t] = s;
    }
}

// Persistent waves: each wave owns RPW consecutive rows. u hoisted to regs;
// next row's 4 loads issued before current row's reduce (2-stage pipeline).
__global__ __launch_bounds__(256) void energies_kernel(
    const float4* __restrict__ enc, const float4* __restrict__ u4,
    float* __restrict__ out) {
    int gw   = (int)((blockIdx.x * blockDim.x + threadIdx.x) >> 6);  // 0..8191
    int lane = threadIdx.x & 63;

    float4 w0 = u4[lane];
    float4 w1 = u4[lane + 64];
    float4 w2 = u4[lane + 128];
    float4 w3 = u4[lane + 192];

    size_t row0 = (size_t)gw * RPW;
    const float4* p = enc + row0 * (HDIM / 4) + lane;

    float4 c0 = p[0], c1 = p[64], c2 = p[128], c3 = p[192];
    #pragma unroll
    for (int r = 0; r < RPW; ++r) {
        float4 n0, n1, n2, n3;
        if (r + 1 < RPW) {
            const float4* q = p + (size_t)(r + 1) * (HDIM / 4);
            n0 = q[0]; n1 = q[64]; n2 = q[128]; n3 = q[192];
        }
        float acc = c0.x * w0.x + c0.y * w0.y + c0.z * w0.z + c0.w * w0.w
                  + c1.x * w1.x + c1.y * w1.y + c1.z * w1.z + c1.w * w1.w
                  + c2.x * w2.x + c2.y * w2.y + c2.z * w2.z + c2.w * w2.w
                  + c3.x * w3.x + c3.y * w3.y + c3.z * w3.z + c3.w * w3.w;
        #pragma unroll
        for (int off = 32; off > 0; off >>= 1)
            acc += __shfl_down(acc, off, 64);
        if (lane == 0) out[row0 + r] = acc;
        if (r + 1 < RPW) { c0 = n0; c1 = n1; c2 = n2; c3 = n3; }
    }
}

// One block per batch row: in-place softmax over SDIM values.  [R2 body]
__global__ __launch_bounds__(1024) void softmax_kernel(float* __restrict__ out) {
    __shared__ float red[16];
    float* row = out + (size_t)blockIdx.x * SDIM;
    int t = threadIdx.x;
    int wave = t >> 6, lane = t & 63;

    float e0 = row[t];
    float e1 = row[t + 1024];
    float e2 = row[t + 2048];
    float e3 = row[t + 3072];

    // block max
    float m = fmaxf(fmaxf(e0, e1), fmaxf(e2, e3));
    #pragma unroll
    for (int off = 32; off > 0; off >>= 1)
        m = fmaxf(m, __shfl_down(m, off, 64));
    if (lane == 0) red[wave] = m;
    __syncthreads();
    if (t < 16) {
        float mm = red[t];
        #pragma unroll
        for (int off = 8; off > 0; off >>= 1)
            mm = fmaxf(mm, __shfl_down(mm, off, 16));
        if (t == 0) red[0] = mm;
    }
    __syncthreads();
    m = red[0];
    __syncthreads();

    // exp + block sum
    float x0 = __expf(e0 - m);
    float x1 = __expf(e1 - m);
    float x2 = __expf(e2 - m);
    float x3 = __expf(e3 - m);
    float s = x0 + x1 + x2 + x3;
    #pragma unroll
    for (int off = 32; off > 0; off >>= 1)
        s += __shfl_down(s, off, 64);
    if (lane == 0) red[wave] = s;
    __syncthreads();
    if (t < 16) {
        float ss = red[t];
        #pragma unroll
        for (int off = 8; off > 0; off >>= 1)
            ss += __shfl_down(ss, off, 16);
        if (t == 0) red[0] = ss;
    }
    __syncthreads();
    float inv = 1.f / red[0];

    row[t]        = x0 * inv;
    row[t + 1024] = x1 * inv;
    row[t + 2048] = x2 * inv;
    row[t + 3072] = x3 * inv;
}

extern "C" void kernel_launch(void* const* d_in, const int* in_sizes, int n_in,
                              void* d_out, int out_size, void* d_ws, size_t ws_size,
                              hipStream_t stream) {
    // inputs: 0=hidden (unused: softmax shift-invariance), 1=encoder_outputs,
    //         2=W, 3=b (unused), 4=v
    const float* enc = (const float*)d_in[1];
    const float* W   = (const float*)d_in[2];
    const float* v   = (const float*)d_in[4];
    float* out = (float*)d_out;
    float* u   = (float*)d_ws;  // HDIM floats = 4 KB scratch

    compute_u_kernel<<<64, 256, 0, stream>>>(W, v, u);

    energies_kernel<<<EBLOCKS, 256, 0, stream>>>(
        (const float4*)enc, (const float4*)u, out);

    softmax_kernel<<<BDIM, 1024, 0, stream>>>(out);
}

// Round 7
// 50.659 us; speedup vs baseline: 1.0438x; 1.0438x over previous
//
#include <hip/hip_runtime.h>

#define HDIM 1024
#define SDIM 4096
#define BDIM 16

// u[h] = sum_k v[k] * W[k*2H + H + h]
// h-split, atomic-free: block b owns h in [16b, 16b+16). Thread t = (kc, hl),
// kc = t>>4 (16 k-chunks of 64), hl = t&15. LDS-reduce over kc, single store.
// No memset needed, no atomics.  [R5 body — measured 50.6 us total]
__global__ __launch_bounds__(256) void compute_u_kernel(
    const float* __restrict__ W, const float* __restrict__ v,
    float* __restrict__ u) {
    __shared__ float part[16][17];  // [kc][hl], +1 pad
    int t  = threadIdx.x;
    int hl = t & 15;
    int kc = t >> 4;
    int h  = blockIdx.x * 16 + hl;
    float acc = 0.f;
    #pragma unroll 8
    for (int i = 0; i < 64; ++i) {
        int k = kc * 64 + i;
        acc = fmaf(v[k], W[(size_t)k * (2 * HDIM) + HDIM + h], acc);
    }
    part[kc][hl] = acc;
    __syncthreads();
    if (t < 16) {
        float s = 0.f;
        #pragma unroll
        for (int i = 0; i < 16; ++i) s += part[i][t];
        u[blockIdx.x * 16 + t] = s;
    }
}

// One wave (64 lanes) per row: energy[row] = dot(enc[row, :], u)
// 1 row/wave, 4x float4/lane, fully coalesced; measured best shape
// (beats 4-rows/wave R3 and persistent 8-rows/wave R6).
__global__ __launch_bounds__(256) void energies_kernel(
    const float4* __restrict__ enc, const float4* __restrict__ u,
    float* __restrict__ out) {
    int wid  = (int)((blockIdx.x * blockDim.x + threadIdx.x) >> 6);
    int lane = threadIdx.x & 63;
    const float4* row = enc + (size_t)wid * (HDIM / 4);
    float acc = 0.f;
    #pragma unroll
    for (int i = 0; i < 4; ++i) {
        float4 e = row[lane + i * 64];
        float4 w = u[lane + i * 64];
        acc += e.x * w.x + e.y * w.y + e.z * w.z + e.w * w.w;
    }
    #pragma unroll
    for (int off = 32; off > 0; off >>= 1)
        acc += __shfl_down(acc, off, 64);
    if (lane == 0) out[wid] = acc;
}

// One block per batch row: in-place softmax over SDIM values.
__global__ __launch_bounds__(1024) void softmax_kernel(float* __restrict__ out) {
    __shared__ float red[16];
    float* row = out + (size_t)blockIdx.x * SDIM;
    int t = threadIdx.x;
    int wave = t >> 6, lane = t & 63;

    float e0 = row[t];
    float e1 = row[t + 1024];
    float e2 = row[t + 2048];
    float e3 = row[t + 3072];

    // block max
    float m = fmaxf(fmaxf(e0, e1), fmaxf(e2, e3));
    #pragma unroll
    for (int off = 32; off > 0; off >>= 1)
        m = fmaxf(m, __shfl_down(m, off, 64));
    if (lane == 0) red[wave] = m;
    __syncthreads();
    if (t < 16) {
        float mm = red[t];
        #pragma unroll
        for (int off = 8; off > 0; off >>= 1)
            mm = fmaxf(mm, __shfl_down(mm, off, 16));
        if (t == 0) red[0] = mm;
    }
    __syncthreads();
    m = red[0];
    __syncthreads();

    // exp + block sum
    float x0 = __expf(e0 - m);
    float x1 = __expf(e1 - m);
    float x2 = __expf(e2 - m);
    float x3 = __expf(e3 - m);
    float s = x0 + x1 + x2 + x3;
    #pragma unroll
    for (int off = 32; off > 0; off >>= 1)
        s += __shfl_down(s, off, 64);
    if (lane == 0) red[wave] = s;
    __syncthreads();
    if (t < 16) {
        float ss = red[t];
        #pragma unroll
        for (int off = 8; off > 0; off >>= 1)
            ss += __shfl_down(ss, off, 16);
        if (t == 0) red[0] = ss;
    }
    __syncthreads();
    float inv = 1.f / red[0];

    row[t]        = x0 * inv;
    row[t + 1024] = x1 * inv;
    row[t + 2048] = x2 * inv;
    row[t + 3072] = x3 * inv;
}

extern "C" void kernel_launch(void* const* d_in, const int* in_sizes, int n_in,
                              void* d_out, int out_size, void* d_ws, size_t ws_size,
                              hipStream_t stream) {
    // inputs: 0=hidden (unused: softmax shift-invariance), 1=encoder_outputs,
    //         2=W, 3=b (unused), 4=v
    const float* enc = (const float*)d_in[1];
    const float* W   = (const float*)d_in[2];
    const float* v   = (const float*)d_in[4];
    float* out = (float*)d_out;
    float* u   = (float*)d_ws;  // HDIM floats = 4 KB scratch

    compute_u_kernel<<<64, 256, 0, stream>>>(W, v, u);

    // 4 waves per 256-thread block, one wave per (b,s) row
    energies_kernel<<<(BDIM * SDIM) / 4, 256, 0, stream>>>(
        (const float4*)enc, (const float4*)u, out);

    softmax_kernel<<<BDIM, 1024, 0, stream>>>(out);
}